// Round 3
// baseline (522.230 us; speedup 1.0000x reference)
//
#include <hip/hip_runtime.h>

// GAT 3-layer (N=50000, E=800000 (+N self loops), H=2, C=64, widths 128)
// Round 17: R14 fused_agg structure restored (best: 45.4us/dispatch) with
// touch-count reduction. Model fitted over R14/R15/R16: duration ~ total
// vector-memory line touches (insensitive to VALU count and wave org).
//   1. Width-adaptive tail: peeled last iteration prefetches tail at width
//      8 (rem>4) / 4 (rem 1..4) / 0 (rem==0); tail STEPs skipped by
//      wave-uniform branches. Loaded slots 24.5 -> ~18.8 avg (-14%).
//   2. BN epilogue removed from fused_agg (no LDS/barrier/atomics; kills
//      ~25MB of write-through atomic traffic seen in WRITE_SIZE). New
//      bn_stats kernel (32 blocks) streams Abf (12.8MB) into exclusive
//      part[32][256] slots; bn_fin unchanged.
// 15 dispatches per call (was 11; +2 bn_stats, launch cost ~1us each).

#define N_NODES 50000
#define N_EDGES 800000
#define ET (N_EDGES + N_NODES)   // 850000 incl self loops
#define FDIM 128
#define SLOPE 0.2f
#define BN_EPS 1e-5f
#define SCAN_NB 196              // ceil(50000/256)
#define HIST_NB 3321             // ceil(ET/256)
#define RPK_NB 216               // ceil(3*WSTRIDE/256)
#define LOG2E 1.44269504088896340736f
#define WSTRIDE 18432            // 9 tiles * 4 ks * 64 lanes * 8
#define BNS_NB 32
#define BNS_STRIDE 1563          // ceil(50000/32)

typedef __attribute__((ext_vector_type(8))) short bf16x8;
typedef __attribute__((ext_vector_type(4))) float f32x4;
typedef __attribute__((ext_vector_type(8))) unsigned short u16x8;

__device__ __forceinline__ unsigned short f2bf(float f) {
  unsigned u = __float_as_uint(f);
  u = u + 0x7fffu + ((u >> 16) & 1u);   // RNE
  return (unsigned short)(u >> 16);
}
__device__ __forceinline__ unsigned packbf(float lo, float hi) {
  return ((unsigned)f2bf(hi) << 16) | (unsigned)f2bf(lo);
}
__device__ __forceinline__ float bflo(unsigned p) { return __uint_as_float(p << 16); }
__device__ __forceinline__ float bfhi(unsigned p) { return __uint_as_float(p & 0xffff0000u); }

// ---------------- combined: hist_rank (blocks 0..HIST_NB) + W repack --------
__global__ __launch_bounds__(256) void build_pre(const int* __restrict__ dst,
                                                 int* __restrict__ counts,
                                                 int* __restrict__ rank,
                                                 const float* __restrict__ W0,
                                                 const float* __restrict__ W1,
                                                 const float* __restrict__ W2,
                                                 const float* __restrict__ as0,
                                                 const float* __restrict__ as1,
                                                 const float* __restrict__ as2,
                                                 const float* __restrict__ ad0,
                                                 const float* __restrict__ ad1,
                                                 const float* __restrict__ ad2,
                                                 unsigned short* __restrict__ Wr) {
  int bid = blockIdx.x;
  if (bid < HIST_NB) {
    int i = bid * 256 + threadIdx.x;
    if (i >= ET) return;
    int d = (i < N_EDGES) ? dst[i] : i - N_EDGES;
    rank[i] = atomicAdd(&counts[d], 1);
    return;
  }
  int i = (bid - HIST_NB) * 256 + threadIdx.x;
  if (i >= 3 * WSTRIDE) return;
  int L = i / WSTRIDE, rem = i % WSTRIDE;
  int t  = rem >> 11;
  int ks = (rem >> 9) & 3;
  int ln = (rem >> 3) & 63;
  int j  = rem & 7;
  int k  = ks * 32 + (ln >> 4) * 8 + j;
  const float* W = (L == 0) ? W0 : ((L == 1) ? W1 : W2);
  float val;
  if (t < 8) {
    int col = t * 16 + (ln & 15);
    val = W[k * 128 + col];
  } else {
    int cl = ln & 15;
    if (cl < 4) {
      int head = cl & 1;
      const float* a = (cl < 2) ? ((L == 0) ? as0 : (L == 1) ? as1 : as2)
                                : ((L == 0) ? ad0 : (L == 1) ? ad1 : ad2);
      float s = 0.f;
      const float* wrow = W + k * 128 + head * 64;
      const float* ah = a + head * 64;
#pragma unroll 8
      for (int c = 0; c < 64; ++c) s = fmaf(wrow[c], ah[c], s);
      val = s * LOG2E;
    } else {
      val = 0.f;
    }
  }
  Wr[i] = f2bf(val);
}

// ---------------- CSR scan ----------------

__global__ __launch_bounds__(256) void scan_blk(const int* __restrict__ counts,
                                                int* __restrict__ rowptr,
                                                int* __restrict__ partials) {
  int i = blockIdx.x * 256 + threadIdx.x;
  int lane = threadIdx.x & 63, wv = threadIdx.x >> 6;
  int c = (i < N_NODES) ? counts[i] : 0;
  int v = c;
#pragma unroll
  for (int off = 1; off < 64; off <<= 1) {
    int u = __shfl_up(v, off);
    if (lane >= off) v += u;
  }
  __shared__ int wsum[4];
  if (lane == 63) wsum[wv] = v;
  __syncthreads();
  int add = 0;
  for (int w = 0; w < wv; ++w) add += wsum[w];
  if (i < N_NODES) rowptr[i] = v - c + add;
  if (threadIdx.x == 255) partials[blockIdx.x] = add + v;
}

__global__ __launch_bounds__(256) void scan_fin(int* __restrict__ rowptr,
                                                const int* __restrict__ partials) {
  __shared__ int sh[256];
  int t = threadIdx.x;
  sh[t] = (t < (int)blockIdx.x && t < SCAN_NB) ? partials[t] : 0;
  __syncthreads();
#pragma unroll
  for (int off = 128; off > 0; off >>= 1) {
    if (t < off) sh[t] += sh[t + off];
    __syncthreads();
  }
  int base = sh[0];
  int i = blockIdx.x * 256 + t;
  if (i < N_NODES) rowptr[i] += base;
  if (i == 0) rowptr[N_NODES] = ET;
}

__global__ __launch_bounds__(256) void scatter_pos(const int* __restrict__ src,
                                                   const int* __restrict__ dst,
                                                   const int* __restrict__ rowptr,
                                                   const int* __restrict__ rank,
                                                   int* __restrict__ csr_src) {
  int i = blockIdx.x * 256 + threadIdx.x;
  if (i >= ET) return;
  int d, s;
  if (i < N_EDGES) { d = dst[i]; s = src[i]; } else { d = s = i - N_EDGES; }
  csr_src[rowptr[d] + rank[i]] = s;
}

// ---------------- BN stats: stream Abf -> part[32][256] (exclusive slots) --
__global__ __launch_bounds__(256) void bn_stats(const unsigned* __restrict__ Abf,
                                                float* __restrict__ part) {
  int tid = threadIdx.x;
  int j = tid & 63;            // u32 slot = channels 2j, 2j+1
  int rg = tid >> 6;           // row group 0..3
  int rs = blockIdx.x * BNS_STRIDE;
  int re = rs + BNS_STRIDE;
  if (re > N_NODES) re = N_NODES;
  float sx = 0.f, sy = 0.f, qx = 0.f, qy = 0.f;
  for (int r = rs + rg; r < re; r += 4) {
    unsigned u = Abf[(size_t)r * 64 + j];
    float x = bflo(u), y = bfhi(u);
    sx += x; sy += y;
    qx = fmaf(x, x, qx); qy = fmaf(y, y, qy);
  }
  __shared__ float red[4][4][64];
  red[rg][0][j] = sx; red[rg][1][j] = sy;
  red[rg][2][j] = qx; red[rg][3][j] = qy;
  __syncthreads();
  if (tid < 64) {
    float a0 = 0.f, a1 = 0.f, a2 = 0.f, a3 = 0.f;
#pragma unroll
    for (int w = 0; w < 4; ++w) {
      a0 += red[w][0][tid]; a1 += red[w][1][tid];
      a2 += red[w][2][tid]; a3 += red[w][3][tid];
    }
    float* slot = part + blockIdx.x * 256;
    slot[2 * tid]           = a0;
    slot[2 * tid + 1]       = a1;
    slot[128 + 2 * tid]     = a2;
    slot[128 + 2 * tid + 1] = a3;
  }
}

// ---------------- BN finalize: part[32][256] -> lsbuf[256]; zero part ------
__global__ __launch_bounds__(128) void bn_fin(float* __restrict__ part,
                                              const float* __restrict__ g,
                                              const float* __restrict__ be,
                                              float* __restrict__ lsbuf) {
  int t = threadIdx.x;   // 0..127
  float s = 0.f, q = 0.f;
#pragma unroll
  for (int k = 0; k < 32; ++k) {
    s += part[k * 256 + t];
    q += part[k * 256 + 128 + t];
    part[k * 256 + t] = 0.f;
    part[k * 256 + 128 + t] = 0.f;
  }
  float mu  = s * (1.f / N_NODES);
  float var = q * (1.f / N_NODES) - mu * mu;
  float sc  = rsqrtf(var + BN_EPS) * g[t];
  lsbuf[t]       = sc;
  lsbuf[128 + t] = be[t] - mu * sc;
}

// ---------------- MFMA gemm (9 tiles: 8 H cols + logit cols) — unchanged ---
__global__ __launch_bounds__(256) void gemm_mfma(const void* __restrict__ Xin,
                                                 const unsigned short* __restrict__ WrL,
                                                 const float* __restrict__ lsbuf,
                                                 unsigned short* __restrict__ Hbf,
                                                 float* __restrict__ als,
                                                 float* __restrict__ ald,
                                                 int inBF) {
  __shared__ unsigned short lds[4][16][128];
  __shared__ float ls_scale[128], ls_shift[128];
  int lane = threadIdx.x & 63;
  int wv   = threadIdx.x >> 6;

  if (inBF) {
    int t = threadIdx.x;
    if (t < 128) {
      ls_scale[t] = lsbuf[t];
      ls_shift[t] = lsbuf[128 + t];
    }
    __syncthreads();
  }

  int row0 = blockIdx.x * 64 + wv * 16;
  int gidx = lane & 15;
  int quad = lane >> 4;
  int rA   = row0 + gidx;
  int rAc  = rA < N_NODES ? rA : N_NODES - 1;
  int koff = quad * 8;

  f32x4 acc[9] = {};
#pragma unroll
  for (int ks = 0; ks < 4; ++ks) {
    int cb = ks * 32 + koff;
    float xv[8];
    if (inBF) {
      const uint4* xr = (const uint4*)((const unsigned*)Xin + (size_t)rAc * 64 + (cb >> 1));
      uint4 xa = *xr;
      xv[0] = bflo(xa.x); xv[1] = bfhi(xa.x);
      xv[2] = bflo(xa.y); xv[3] = bfhi(xa.y);
      xv[4] = bflo(xa.z); xv[5] = bfhi(xa.z);
      xv[6] = bflo(xa.w); xv[7] = bfhi(xa.w);
    } else {
      const float4* xr = (const float4*)((const float*)Xin + (size_t)rAc * FDIM + cb);
      float4 xa = xr[0], xb = xr[1];
      xv[0] = xa.x; xv[1] = xa.y; xv[2] = xa.z; xv[3] = xa.w;
      xv[4] = xb.x; xv[5] = xb.y; xv[6] = xb.z; xv[7] = xb.w;
    }
    bf16x8 afrag;
    if (inBF) {
#pragma unroll
      for (int j = 0; j < 8; ++j) {
        int c = cb + j;
        float v = fmaf(xv[j], ls_scale[c], ls_shift[c]);
        v = v > 0.f ? v : 0.f;
        afrag[j] = (short)f2bf(v);
      }
    } else {
#pragma unroll
      for (int j = 0; j < 8; ++j) afrag[j] = (short)f2bf(xv[j]);
    }
#pragma unroll
    for (int t = 0; t < 9; ++t) {
      bf16x8 bfrag = *(const bf16x8*)(WrL + ((size_t)((t * 4 + ks) * 64 + lane)) * 8);
      acc[t] = __builtin_amdgcn_mfma_f32_16x16x32_bf16(afrag, bfrag, acc[t], 0, 0, 0);
    }
  }

  if (gidx < 4) {
    float* dp = (gidx < 2) ? als : ald;
    int hd = gidx & 1;
#pragma unroll
    for (int r = 0; r < 4; ++r) {
      int row = row0 + quad * 4 + r;
      if (row < N_NODES) dp[row * 2 + hd] = acc[8][r];
    }
  }

#pragma unroll
  for (int t = 0; t < 8; ++t)
#pragma unroll
    for (int r = 0; r < 4; ++r)
      lds[wv][quad * 4 + r][t * 16 + gidx] = f2bf(acc[t][r]);
  __syncthreads();
#pragma unroll
  for (int it = 0; it < 4; ++it) {
    int rloc = it * 4 + quad;
    int row = row0 + rloc;
    if (row < N_NODES)
      *(u16x8*)(Hbf + (size_t)row * FDIM + gidx * 8) = *(u16x8*)&lds[wv][rloc][gidx * 8];
  }
}

// ---------------- fused softmax-aggregate (R14 layout, adaptive tail) ------
// One wave per node; lane owns channels 2l,2l+1; lanes 0-31 head 0,
// 32-63 head 1. exp2 logits (log2e baked into W*a), no max shift.
// 8-deep register prefetch; main loop unclamped/unmasked; peeled last
// iteration prefetches the tail at width 8 / 4 / 0; tail STEPs gated by
// wave-uniform scalar branches. No LDS, no barrier, no BN epilogue.
// mode 0: write Abf bf16-pair. mode 2: head-mean + b2 -> out fp32 [N,64].
__global__ __launch_bounds__(256) void fused_agg(const int* __restrict__ rowptr,
                                                 const int* __restrict__ csr_src,
                                                 const unsigned* __restrict__ H2,
                                                 const float* __restrict__ als,
                                                 const float* __restrict__ ald,
                                                 unsigned* __restrict__ Abf,
                                                 float* __restrict__ out,
                                                 const float* __restrict__ b2,
                                                 int mode) {
  int lane = threadIdx.x & 63;
  bool hi = lane >= 32;
  int n = __builtin_amdgcn_readfirstlane((blockIdx.x * 256 + threadIdx.x) >> 6);
  int beg = rowptr[n], end = rowptr[n + 1];
  int deg = end - beg;                   // >= 1 (self loop)
  int last = end - 1;
  float2 adv = ((const float2*)ald)[n];
  float advh = hi ? adv.y : adv.x;

  int nfull = deg >> 3;
  int rem = deg & 7;

  // prologue: block 0 (clamped; exact when deg>=8)
  int sa[8]; float2 aa[8]; unsigned ha[8];
#pragma unroll
  for (int i = 0; i < 8; ++i) {
    int idx = beg + i; idx = idx > last ? last : idx;
    sa[i] = csr_src[idx];
  }
#pragma unroll
  for (int i = 0; i < 8; ++i) {
    aa[i] = ((const float2*)als)[sa[i]];
    ha[i] = H2[(size_t)sa[i] * 64 + lane];
  }

  float l = 0.f, ox = 0.f, oy = 0.f;

#define STEPU(i) { \
    float v_ = (hi ? aa[i].y : aa[i].x) + advh; \
    v_ = fmaxf(v_, SLOPE * v_); \
    float e_ = exp2f(v_); \
    l += e_; \
    ox = fmaf(e_, bflo(ha[i]), ox); \
    oy = fmaf(e_, bfhi(ha[i]), oy); }
#define STEPM(i) { if (i < rem) STEPU(i) }

  // main loop: compute block b-1, prefetch full block b (exact, unclamped)
  for (int b = 1; b < nfull; ++b) {
    int base = beg + b * 8;
    int sn[8]; float2 an[8]; unsigned hn[8];
#pragma unroll
    for (int i = 0; i < 8; ++i) sn[i] = csr_src[base + i];
#pragma unroll
    for (int i = 0; i < 8; ++i) {
      an[i] = ((const float2*)als)[sn[i]];
      hn[i] = H2[(size_t)sn[i] * 64 + lane];
    }
    STEPU(0); STEPU(1); STEPU(2); STEPU(3);
    STEPU(4); STEPU(5); STEPU(6); STEPU(7);
#pragma unroll
    for (int i = 0; i < 8; ++i) { aa[i] = an[i]; ha[i] = hn[i]; }
  }

  // peeled last full-block iteration: prefetch tail at adaptive width
  if (nfull) {
    int base = beg + nfull * 8;
    int sn[8]; float2 an[8]; unsigned hn[8];
    if (rem > 4) {
#pragma unroll
      for (int i = 0; i < 8; ++i) {
        int idx = base + i; idx = idx > last ? last : idx;
        sn[i] = csr_src[idx];
      }
#pragma unroll
      for (int i = 0; i < 8; ++i) {
        an[i] = ((const float2*)als)[sn[i]];
        hn[i] = H2[(size_t)sn[i] * 64 + lane];
      }
    } else if (rem) {
#pragma unroll
      for (int i = 0; i < 4; ++i) {
        int idx = base + i; idx = idx > last ? last : idx;
        sn[i] = csr_src[idx];
      }
#pragma unroll
      for (int i = 0; i < 4; ++i) {
        an[i] = ((const float2*)als)[sn[i]];
        hn[i] = H2[(size_t)sn[i] * 64 + lane];
      }
    }
    STEPU(0); STEPU(1); STEPU(2); STEPU(3);
    STEPU(4); STEPU(5); STEPU(6); STEPU(7);
    if (rem > 4) {
#pragma unroll
      for (int i = 0; i < 8; ++i) { aa[i] = an[i]; ha[i] = hn[i]; }
    } else if (rem) {
#pragma unroll
      for (int i = 0; i < 4; ++i) { aa[i] = an[i]; ha[i] = hn[i]; }
    }
  }

  // tail: wave-uniform gated STEPs
  if (rem > 4) {
    STEPM(0); STEPM(1); STEPM(2); STEPM(3);
    STEPM(4); STEPM(5); STEPM(6); STEPM(7);
  } else if (rem) {
    STEPM(0); STEPM(1); STEPM(2); STEPM(3);
  }
#undef STEPU
#undef STEPM

  float inv = 1.f / (l + 1e-16f);
  ox *= inv; oy *= inv;

  if (mode == 0) {
    Abf[(size_t)n * 64 + lane] = packbf(ox, oy);
  } else {
    float px = __shfl_xor(ox, 32);
    float py = __shfl_xor(oy, 32);
    if (lane < 32) {
      int c = lane * 2;
      float2 outv = {0.5f * (ox + px) + b2[c], 0.5f * (oy + py) + b2[c + 1]};
      *(float2*)(out + (size_t)n * 64 + c) = outv;
    }
  }
}

extern "C" void kernel_launch(void* const* d_in, const int* in_sizes, int n_in,
                              void* d_out, int out_size, void* d_ws, size_t ws_size,
                              hipStream_t stream) {
  const float* x  = (const float*)d_in[0];
  const int*   ei = (const int*)d_in[1];
  const int* src = ei;
  const int* dst = ei + N_EDGES;

  const float* W[3]    = {(const float*)d_in[2],  (const float*)d_in[8],  (const float*)d_in[14]};
  const float* asrc[3] = {(const float*)d_in[3],  (const float*)d_in[9],  (const float*)d_in[15]};
  const float* adst[3] = {(const float*)d_in[4],  (const float*)d_in[10], (const float*)d_in[16]};
  const float* g[2]    = {(const float*)d_in[6],  (const float*)d_in[12]};
  const float* be[2]   = {(const float*)d_in[7],  (const float*)d_in[13]};
  const float* b2      = (const float*)d_in[17];

  // workspace (4-byte units, regions 16B-aligned).
  int*   counts   = (int*)d_ws;                  // 50048
  float* part     = (float*)(counts + 50048);    // 8192 (32x256 BN slots)
  int*   rowptr   = (int*)(part + 8192);         // 50048
  int*   partials = rowptr + 50048;              // 256
  int*   rank     = partials + 256;              // 850048
  int*   csr_src  = rank + 850048;               // 850048
  float* lsbuf    = (float*)(csr_src + 850048);  // 256 scale|shift
  float* als      = lsbuf + 256;                 // 100096
  float* ald      = als + 100096;                // 100096
  unsigned short* Wr  = (unsigned short*)(ald + 100096);   // 3*WSTRIDE u16
  unsigned short* Hbf = Wr + 3 * WSTRIDE + 128;            // pad to 16B align
  unsigned* Abf   = (unsigned*)(Hbf + (size_t)N_NODES * FDIM);

  // ---- setup: zero counts+part, hist+repack, scan, scatter ----
  hipMemsetAsync(counts, 0, (50048 + 8192) * sizeof(int), stream);
  build_pre<<<HIST_NB + RPK_NB, 256, 0, stream>>>(
      dst, counts, rank, W[0], W[1], W[2],
      asrc[0], asrc[1], asrc[2], adst[0], adst[1], adst[2], Wr);
  scan_blk<<<SCAN_NB, 256, 0, stream>>>(counts, rowptr, partials);
  scan_fin<<<SCAN_NB, 256, 0, stream>>>(rowptr, partials);
  scatter_pos<<<(ET + 255) / 256, 256, 0, stream>>>(src, dst, rowptr, rank, csr_src);

  const int gemm_grid = (N_NODES + 63) / 64;
  const int agg_grid  = N_NODES * 64 / 256;   // 12500, one wave per node

  for (int L = 0; L < 3; ++L) {
    const void* fin = (L == 0) ? (const void*)x : (const void*)Abf;
    int inBF = (L > 0);
    gemm_mfma<<<gemm_grid, 256, 0, stream>>>(fin, Wr + (size_t)L * WSTRIDE, lsbuf,
                                             Hbf, als, ald, inBF);
    fused_agg<<<agg_grid, 256, 0, stream>>>(rowptr, csr_src, (const unsigned*)Hbf,
                                            als, ald, Abf, (float*)d_out, b2,
                                            (L == 2) ? 2 : 0);
    if (L < 2) {
      bn_stats<<<BNS_NB, 256, 0, stream>>>(Abf, part);
      bn_fin<<<1, 128, 0, stream>>>(part, g[L], be[L], lsbuf);
    }
  }
}

// Round 6
// 345.724 us; speedup vs baseline: 1.5105x; 1.5105x over previous
//
#include <hip/hip_runtime.h>

// GAT 3-layer (N=50000, E=800000 (+N self loops), H=2, C=64, widths 128)
// Round 20: R19 resubmission (2x "container failed twice" with no diag —
// presumed infra; R19 audit found no OOB/graph-capture hazard). One extra
// conservative change: bn_fin back to 256 threads/block (512 was the only
// block size never used in a passing round); 2-segment x 128-slot split.
// Structure:
//   - bn_stats: 256 blocks (1/CU), exclusive slots in part[256][256] which
//     ALIASES dead rank[] (rank dead after scatter_pos; no ws growth).
//     uint2 loads, no atomics, no zeroing (slots fully overwritten).
//   - fused_agg: R14 layout + adaptive tail, no BN epilogue (R17,verified).
//   - workspace layout byte-identical to R14/R17 (known to fit).
// 15 dispatches per call.

#define N_NODES 50000
#define N_EDGES 800000
#define ET (N_EDGES + N_NODES)   // 850000 incl self loops
#define FDIM 128
#define SLOPE 0.2f
#define BN_EPS 1e-5f
#define SCAN_NB 196              // ceil(50000/256)
#define HIST_NB 3321             // ceil(ET/256)
#define RPK_NB 216               // ceil(3*WSTRIDE/256)
#define LOG2E 1.44269504088896340736f
#define WSTRIDE 18432            // 9 tiles * 4 ks * 64 lanes * 8
#define BNS_NB 256
#define BNS_STRIDE 196           // ceil(50000/256)

typedef __attribute__((ext_vector_type(8))) short bf16x8;
typedef __attribute__((ext_vector_type(4))) float f32x4;
typedef __attribute__((ext_vector_type(8))) unsigned short u16x8;

__device__ __forceinline__ unsigned short f2bf(float f) {
  unsigned u = __float_as_uint(f);
  u = u + 0x7fffu + ((u >> 16) & 1u);   // RNE
  return (unsigned short)(u >> 16);
}
__device__ __forceinline__ unsigned packbf(float lo, float hi) {
  return ((unsigned)f2bf(hi) << 16) | (unsigned)f2bf(lo);
}
__device__ __forceinline__ float bflo(unsigned p) { return __uint_as_float(p << 16); }
__device__ __forceinline__ float bfhi(unsigned p) { return __uint_as_float(p & 0xffff0000u); }

// ---------------- combined: hist_rank (blocks 0..HIST_NB) + W repack --------
__global__ __launch_bounds__(256) void build_pre(const int* __restrict__ dst,
                                                 int* __restrict__ counts,
                                                 int* __restrict__ rank,
                                                 const float* __restrict__ W0,
                                                 const float* __restrict__ W1,
                                                 const float* __restrict__ W2,
                                                 const float* __restrict__ as0,
                                                 const float* __restrict__ as1,
                                                 const float* __restrict__ as2,
                                                 const float* __restrict__ ad0,
                                                 const float* __restrict__ ad1,
                                                 const float* __restrict__ ad2,
                                                 unsigned short* __restrict__ Wr) {
  int bid = blockIdx.x;
  if (bid < HIST_NB) {
    int i = bid * 256 + threadIdx.x;
    if (i >= ET) return;
    int d = (i < N_EDGES) ? dst[i] : i - N_EDGES;
    rank[i] = atomicAdd(&counts[d], 1);
    return;
  }
  int i = (bid - HIST_NB) * 256 + threadIdx.x;
  if (i >= 3 * WSTRIDE) return;
  int L = i / WSTRIDE, rem = i % WSTRIDE;
  int t  = rem >> 11;
  int ks = (rem >> 9) & 3;
  int ln = (rem >> 3) & 63;
  int j  = rem & 7;
  int k  = ks * 32 + (ln >> 4) * 8 + j;
  const float* W = (L == 0) ? W0 : ((L == 1) ? W1 : W2);
  float val;
  if (t < 8) {
    int col = t * 16 + (ln & 15);
    val = W[k * 128 + col];
  } else {
    int cl = ln & 15;
    if (cl < 4) {
      int head = cl & 1;
      const float* a = (cl < 2) ? ((L == 0) ? as0 : (L == 1) ? as1 : as2)
                                : ((L == 0) ? ad0 : (L == 1) ? ad1 : ad2);
      float s = 0.f;
      const float* wrow = W + k * 128 + head * 64;
      const float* ah = a + head * 64;
#pragma unroll 8
      for (int c = 0; c < 64; ++c) s = fmaf(wrow[c], ah[c], s);
      val = s * LOG2E;
    } else {
      val = 0.f;
    }
  }
  Wr[i] = f2bf(val);
}

// ---------------- CSR scan ----------------

__global__ __launch_bounds__(256) void scan_blk(const int* __restrict__ counts,
                                                int* __restrict__ rowptr,
                                                int* __restrict__ partials) {
  int i = blockIdx.x * 256 + threadIdx.x;
  int lane = threadIdx.x & 63, wv = threadIdx.x >> 6;
  int c = (i < N_NODES) ? counts[i] : 0;
  int v = c;
#pragma unroll
  for (int off = 1; off < 64; off <<= 1) {
    int u = __shfl_up(v, off);
    if (lane >= off) v += u;
  }
  __shared__ int wsum[4];
  if (lane == 63) wsum[wv] = v;
  __syncthreads();
  int add = 0;
  for (int w = 0; w < wv; ++w) add += wsum[w];
  if (i < N_NODES) rowptr[i] = v - c + add;
  if (threadIdx.x == 255) partials[blockIdx.x] = add + v;
}

__global__ __launch_bounds__(256) void scan_fin(int* __restrict__ rowptr,
                                                const int* __restrict__ partials) {
  __shared__ int sh[256];
  int t = threadIdx.x;
  sh[t] = (t < (int)blockIdx.x && t < SCAN_NB) ? partials[t] : 0;
  __syncthreads();
#pragma unroll
  for (int off = 128; off > 0; off >>= 1) {
    if (t < off) sh[t] += sh[t + off];
    __syncthreads();
  }
  int base = sh[0];
  int i = blockIdx.x * 256 + t;
  if (i < N_NODES) rowptr[i] += base;
  if (i == 0) rowptr[N_NODES] = ET;
}

__global__ __launch_bounds__(256) void scatter_pos(const int* __restrict__ src,
                                                   const int* __restrict__ dst,
                                                   const int* __restrict__ rowptr,
                                                   const int* __restrict__ rank,
                                                   int* __restrict__ csr_src) {
  int i = blockIdx.x * 256 + threadIdx.x;
  if (i >= ET) return;
  int d, s;
  if (i < N_EDGES) { d = dst[i]; s = src[i]; } else { d = s = i - N_EDGES; }
  csr_src[rowptr[d] + rank[i]] = s;
}

// ---------------- BN stats: stream Abf -> part[256][256] (exclusive slots) -
// 256 blocks x 256 threads; uint2 loads (4 channels/thread, 8 row groups).
// 'part' aliases the dead rank[] buffer (see kernel_launch).
__global__ __launch_bounds__(256) void bn_stats(const unsigned* __restrict__ Abf,
                                                float* __restrict__ part) {
  int tid = threadIdx.x;
  int j2 = tid & 31;           // uint2 slot: channels 4*j2 .. 4*j2+3
  int rg = tid >> 5;           // row group 0..7
  int rs = blockIdx.x * BNS_STRIDE;
  int re = rs + BNS_STRIDE;
  if (re > N_NODES) re = N_NODES;
  float s0 = 0.f, s1 = 0.f, s2 = 0.f, s3 = 0.f;
  float q0 = 0.f, q1 = 0.f, q2 = 0.f, q3 = 0.f;
  for (int r = rs + rg; r < re; r += 8) {
    uint2 u = *(const uint2*)(Abf + (size_t)r * 64 + 2 * j2);
    float x0 = bflo(u.x), x1 = bfhi(u.x), x2 = bflo(u.y), x3 = bfhi(u.y);
    s0 += x0; s1 += x1; s2 += x2; s3 += x3;
    q0 = fmaf(x0, x0, q0); q1 = fmaf(x1, x1, q1);
    q2 = fmaf(x2, x2, q2); q3 = fmaf(x3, x3, q3);
  }
  __shared__ float red[8][32][8];    // [rg][j2][stat]
  red[rg][j2][0] = s0; red[rg][j2][1] = s1;
  red[rg][j2][2] = s2; red[rg][j2][3] = s3;
  red[rg][j2][4] = q0; red[rg][j2][5] = q1;
  red[rg][j2][6] = q2; red[rg][j2][7] = q3;
  __syncthreads();
  if (tid < 128) {
    int c = tid;                     // channel
    float a = 0.f, q = 0.f;
#pragma unroll
    for (int w = 0; w < 8; ++w) {
      a += red[w][c >> 2][c & 3];
      q += red[w][c >> 2][4 + (c & 3)];
    }
    float* slot = part + blockIdx.x * 256;
    slot[c]       = a;
    slot[128 + c] = q;
  }
}

// ---------------- BN finalize: part[256][256] -> lsbuf[256] ---------------
// 256 threads: 2 segments of 128 slots each, LDS combine. No zeroing.
__global__ __launch_bounds__(256) void bn_fin(const float* __restrict__ part,
                                              const float* __restrict__ g,
                                              const float* __restrict__ be,
                                              float* __restrict__ lsbuf) {
  int tid = threadIdx.x;
  int t = tid & 127, seg = tid >> 7;   // seg 0..1
  float s = 0.f, q = 0.f;
#pragma unroll 4
  for (int k = seg * 128; k < seg * 128 + 128; ++k) {
    s += part[k * 256 + t];
    q += part[k * 256 + 128 + t];
  }
  __shared__ float sh[2][2][128];
  sh[seg][0][t] = s;
  sh[seg][1][t] = q;
  __syncthreads();
  if (tid < 128) {
    float ss = sh[0][0][tid] + sh[1][0][tid];
    float qq = sh[0][1][tid] + sh[1][1][tid];
    float mu  = ss * (1.f / N_NODES);
    float var = qq * (1.f / N_NODES) - mu * mu;
    float sc  = rsqrtf(var + BN_EPS) * g[tid];
    lsbuf[tid]       = sc;
    lsbuf[128 + tid] = be[tid] - mu * sc;
  }
}

// ---------------- MFMA gemm (9 tiles: 8 H cols + logit cols) — unchanged ---
__global__ __launch_bounds__(256) void gemm_mfma(const void* __restrict__ Xin,
                                                 const unsigned short* __restrict__ WrL,
                                                 const float* __restrict__ lsbuf,
                                                 unsigned short* __restrict__ Hbf,
                                                 float* __restrict__ als,
                                                 float* __restrict__ ald,
                                                 int inBF) {
  __shared__ unsigned short lds[4][16][128];
  __shared__ float ls_scale[128], ls_shift[128];
  int lane = threadIdx.x & 63;
  int wv   = threadIdx.x >> 6;

  if (inBF) {
    int t = threadIdx.x;
    if (t < 128) {
      ls_scale[t] = lsbuf[t];
      ls_shift[t] = lsbuf[128 + t];
    }
    __syncthreads();
  }

  int row0 = blockIdx.x * 64 + wv * 16;
  int gidx = lane & 15;
  int quad = lane >> 4;
  int rA   = row0 + gidx;
  int rAc  = rA < N_NODES ? rA : N_NODES - 1;
  int koff = quad * 8;

  f32x4 acc[9] = {};
#pragma unroll
  for (int ks = 0; ks < 4; ++ks) {
    int cb = ks * 32 + koff;
    float xv[8];
    if (inBF) {
      const uint4* xr = (const uint4*)((const unsigned*)Xin + (size_t)rAc * 64 + (cb >> 1));
      uint4 xa = *xr;
      xv[0] = bflo(xa.x); xv[1] = bfhi(xa.x);
      xv[2] = bflo(xa.y); xv[3] = bfhi(xa.y);
      xv[4] = bflo(xa.z); xv[5] = bfhi(xa.z);
      xv[6] = bflo(xa.w); xv[7] = bfhi(xa.w);
    } else {
      const float4* xr = (const float4*)((const float*)Xin + (size_t)rAc * FDIM + cb);
      float4 xa = xr[0], xb = xr[1];
      xv[0] = xa.x; xv[1] = xa.y; xv[2] = xa.z; xv[3] = xa.w;
      xv[4] = xb.x; xv[5] = xb.y; xv[6] = xb.z; xv[7] = xb.w;
    }
    bf16x8 afrag;
    if (inBF) {
#pragma unroll
      for (int j = 0; j < 8; ++j) {
        int c = cb + j;
        float v = fmaf(xv[j], ls_scale[c], ls_shift[c]);
        v = v > 0.f ? v : 0.f;
        afrag[j] = (short)f2bf(v);
      }
    } else {
#pragma unroll
      for (int j = 0; j < 8; ++j) afrag[j] = (short)f2bf(xv[j]);
    }
#pragma unroll
    for (int t = 0; t < 9; ++t) {
      bf16x8 bfrag = *(const bf16x8*)(WrL + ((size_t)((t * 4 + ks) * 64 + lane)) * 8);
      acc[t] = __builtin_amdgcn_mfma_f32_16x16x32_bf16(afrag, bfrag, acc[t], 0, 0, 0);
    }
  }

  if (gidx < 4) {
    float* dp = (gidx < 2) ? als : ald;
    int hd = gidx & 1;
#pragma unroll
    for (int r = 0; r < 4; ++r) {
      int row = row0 + quad * 4 + r;
      if (row < N_NODES) dp[row * 2 + hd] = acc[8][r];
    }
  }

#pragma unroll
  for (int t = 0; t < 8; ++t)
#pragma unroll
    for (int r = 0; r < 4; ++r)
      lds[wv][quad * 4 + r][t * 16 + gidx] = f2bf(acc[t][r]);
  __syncthreads();
#pragma unroll
  for (int it = 0; it < 4; ++it) {
    int rloc = it * 4 + quad;
    int row = row0 + rloc;
    if (row < N_NODES)
      *(u16x8*)(Hbf + (size_t)row * FDIM + gidx * 8) = *(u16x8*)&lds[wv][rloc][gidx * 8];
  }
}

// ---------------- fused softmax-aggregate (R14 layout, adaptive tail) ------
__global__ __launch_bounds__(256) void fused_agg(const int* __restrict__ rowptr,
                                                 const int* __restrict__ csr_src,
                                                 const unsigned* __restrict__ H2,
                                                 const float* __restrict__ als,
                                                 const float* __restrict__ ald,
                                                 unsigned* __restrict__ Abf,
                                                 float* __restrict__ out,
                                                 const float* __restrict__ b2,
                                                 int mode) {
  int lane = threadIdx.x & 63;
  bool hi = lane >= 32;
  int n = __builtin_amdgcn_readfirstlane((blockIdx.x * 256 + threadIdx.x) >> 6);
  int beg = rowptr[n], end = rowptr[n + 1];
  int deg = end - beg;                   // >= 1 (self loop)
  int last = end - 1;
  float2 adv = ((const float2*)ald)[n];
  float advh = hi ? adv.y : adv.x;

  int nfull = deg >> 3;
  int rem = deg & 7;

  // prologue: block 0 (clamped; exact when deg>=8)
  int sa[8]; float2 aa[8]; unsigned ha[8];
#pragma unroll
  for (int i = 0; i < 8; ++i) {
    int idx = beg + i; idx = idx > last ? last : idx;
    sa[i] = csr_src[idx];
  }
#pragma unroll
  for (int i = 0; i < 8; ++i) {
    aa[i] = ((const float2*)als)[sa[i]];
    ha[i] = H2[(size_t)sa[i] * 64 + lane];
  }

  float l = 0.f, ox = 0.f, oy = 0.f;

#define STEPU(i) { \
    float v_ = (hi ? aa[i].y : aa[i].x) + advh; \
    v_ = fmaxf(v_, SLOPE * v_); \
    float e_ = exp2f(v_); \
    l += e_; \
    ox = fmaf(e_, bflo(ha[i]), ox); \
    oy = fmaf(e_, bfhi(ha[i]), oy); }
#define STEPM(i) { if (i < rem) STEPU(i) }

  // main loop: compute block b-1, prefetch full block b (exact, unclamped)
  for (int b = 1; b < nfull; ++b) {
    int base = beg + b * 8;
    int sn[8]; float2 an[8]; unsigned hn[8];
#pragma unroll
    for (int i = 0; i < 8; ++i) sn[i] = csr_src[base + i];
#pragma unroll
    for (int i = 0; i < 8; ++i) {
      an[i] = ((const float2*)als)[sn[i]];
      hn[i] = H2[(size_t)sn[i] * 64 + lane];
    }
    STEPU(0); STEPU(1); STEPU(2); STEPU(3);
    STEPU(4); STEPU(5); STEPU(6); STEPU(7);
#pragma unroll
    for (int i = 0; i < 8; ++i) { aa[i] = an[i]; ha[i] = hn[i]; }
  }

  // peeled last full-block iteration: prefetch tail at adaptive width
  if (nfull) {
    int base = beg + nfull * 8;
    int sn[8]; float2 an[8]; unsigned hn[8];
    if (rem > 4) {
#pragma unroll
      for (int i = 0; i < 8; ++i) {
        int idx = base + i; idx = idx > last ? last : idx;
        sn[i] = csr_src[idx];
      }
#pragma unroll
      for (int i = 0; i < 8; ++i) {
        an[i] = ((const float2*)als)[sn[i]];
        hn[i] = H2[(size_t)sn[i] * 64 + lane];
      }
    } else if (rem) {
#pragma unroll
      for (int i = 0; i < 4; ++i) {
        int idx = base + i; idx = idx > last ? last : idx;
        sn[i] = csr_src[idx];
      }
#pragma unroll
      for (int i = 0; i < 4; ++i) {
        an[i] = ((const float2*)als)[sn[i]];
        hn[i] = H2[(size_t)sn[i] * 64 + lane];
      }
    }
    STEPU(0); STEPU(1); STEPU(2); STEPU(3);
    STEPU(4); STEPU(5); STEPU(6); STEPU(7);
    if (rem > 4) {
#pragma unroll
      for (int i = 0; i < 8; ++i) { aa[i] = an[i]; ha[i] = hn[i]; }
    } else if (rem) {
#pragma unroll
      for (int i = 0; i < 4; ++i) { aa[i] = an[i]; ha[i] = hn[i]; }
    }
  }

  // tail: wave-uniform gated STEPs
  if (rem > 4) {
    STEPM(0); STEPM(1); STEPM(2); STEPM(3);
    STEPM(4); STEPM(5); STEPM(6); STEPM(7);
  } else if (rem) {
    STEPM(0); STEPM(1); STEPM(2); STEPM(3);
  }
#undef STEPU
#undef STEPM

  float inv = 1.f / (l + 1e-16f);
  ox *= inv; oy *= inv;

  if (mode == 0) {
    Abf[(size_t)n * 64 + lane] = packbf(ox, oy);
  } else {
    float px = __shfl_xor(ox, 32);
    float py = __shfl_xor(oy, 32);
    if (lane < 32) {
      int c = lane * 2;
      float2 outv = {0.5f * (ox + px) + b2[c], 0.5f * (oy + py) + b2[c + 1]};
      *(float2*)(out + (size_t)n * 64 + c) = outv;
    }
  }
}

extern "C" void kernel_launch(void* const* d_in, const int* in_sizes, int n_in,
                              void* d_out, int out_size, void* d_ws, size_t ws_size,
                              hipStream_t stream) {
  const float* x  = (const float*)d_in[0];
  const int*   ei = (const int*)d_in[1];
  const int* src = ei;
  const int* dst = ei + N_EDGES;

  const float* W[3]    = {(const float*)d_in[2],  (const float*)d_in[8],  (const float*)d_in[14]};
  const float* asrc[3] = {(const float*)d_in[3],  (const float*)d_in[9],  (const float*)d_in[15]};
  const float* adst[3] = {(const float*)d_in[4],  (const float*)d_in[10], (const float*)d_in[16]};
  const float* g[2]    = {(const float*)d_in[6],  (const float*)d_in[12]};
  const float* be[2]   = {(const float*)d_in[7],  (const float*)d_in[13]};
  const float* b2      = (const float*)d_in[17];

  // workspace (4-byte units, regions 16B-aligned) — byte-identical to R14/R17.
  int*   counts   = (int*)d_ws;                  // 50048
  float* part8    = (float*)(counts + 50048);    // 8192 (legacy slot, unused)
  int*   rowptr   = (int*)(part8 + 8192);        // 50048
  int*   partials = rowptr + 50048;              // 256
  int*   rank     = partials + 256;              // 850048
  int*   csr_src  = rank + 850048;               // 850048
  float* lsbuf    = (float*)(csr_src + 850048);  // 256 scale|shift
  float* als      = lsbuf + 256;                 // 100096
  float* ald      = als + 100096;                // 100096
  unsigned short* Wr  = (unsigned short*)(ald + 100096);   // 3*WSTRIDE u16
  unsigned short* Hbf = Wr + 3 * WSTRIDE + 128;            // pad to 16B align
  unsigned* Abf   = (unsigned*)(Hbf + (size_t)N_NODES * FDIM);

  // BN partials (256x256 floats) alias the rank buffer: rank is dead after
  // scatter_pos, bn_stats runs strictly later. No workspace growth.
  float* part = (float*)rank;

  // ---- setup: zero counts, hist+repack, scan, scatter ----
  hipMemsetAsync(counts, 0, 50048 * sizeof(int), stream);
  build_pre<<<HIST_NB + RPK_NB, 256, 0, stream>>>(
      dst, counts, rank, W[0], W[1], W[2],
      asrc[0], asrc[1], asrc[2], adst[0], adst[1], adst[2], Wr);
  scan_blk<<<SCAN_NB, 256, 0, stream>>>(counts, rowptr, partials);
  scan_fin<<<SCAN_NB, 256, 0, stream>>>(rowptr, partials);
  scatter_pos<<<(ET + 255) / 256, 256, 0, stream>>>(src, dst, rowptr, rank, csr_src);

  const int gemm_grid = (N_NODES + 63) / 64;
  const int agg_grid  = N_NODES * 64 / 256;   // 12500, one wave per node

  for (int L = 0; L < 3; ++L) {
    const void* fin = (L == 0) ? (const void*)x : (const void*)Abf;
    int inBF = (L > 0);
    gemm_mfma<<<gemm_grid, 256, 0, stream>>>(fin, Wr + (size_t)L * WSTRIDE, lsbuf,
                                             Hbf, als, ald, inBF);
    fused_agg<<<agg_grid, 256, 0, stream>>>(rowptr, csr_src, (const unsigned*)Hbf,
                                            als, ald, Abf, (float*)d_out, b2,
                                            (L == 2) ? 2 : 0);
    if (L < 2) {
      bn_stats<<<BNS_NB, 256, 0, stream>>>(Abf, part);
      bn_fin<<<1, 256, 0, stream>>>(part, g[L], be[L], lsbuf);
    }
  }
}

// Round 7
// 325.157 us; speedup vs baseline: 1.6061x; 1.0633x over previous
//
#include <hip/hip_runtime.h>

// GAT 3-layer (N=50000, E=800000 (+N self loops), H=2, C=64, widths 128)
// Round 21: recombine the two verified wins. R20 post-mortem: adaptive-tail
// fused_agg got faster (dropped out of top-5, <=43us) but the BN split cost
// ~40us serial (2x latency-bound bn_stats + 4 launches) -> total 345.7.
// R21 = R14 structure (BN stats in fused_agg epilogue: LDS pre-reduction +
// 800K atomics into part[32][256], measured fine inside R14's 45.4us) with
// the R17 adaptive-tail main loop (verified -5us/dispatch). bn_stats gone;
// bn_fin back to R14 form (consume + zero part). 11 dispatches; workspace
// layout byte-identical to R14/R17/R20.

#define N_NODES 50000
#define N_EDGES 800000
#define ET (N_EDGES + N_NODES)   // 850000 incl self loops
#define FDIM 128
#define SLOPE 0.2f
#define BN_EPS 1e-5f
#define SCAN_NB 196              // ceil(50000/256)
#define HIST_NB 3321             // ceil(ET/256)
#define RPK_NB 216               // ceil(3*WSTRIDE/256)
#define LOG2E 1.44269504088896340736f
#define WSTRIDE 18432            // 9 tiles * 4 ks * 64 lanes * 8

typedef __attribute__((ext_vector_type(8))) short bf16x8;
typedef __attribute__((ext_vector_type(4))) float f32x4;
typedef __attribute__((ext_vector_type(8))) unsigned short u16x8;

__device__ __forceinline__ unsigned short f2bf(float f) {
  unsigned u = __float_as_uint(f);
  u = u + 0x7fffu + ((u >> 16) & 1u);   // RNE
  return (unsigned short)(u >> 16);
}
__device__ __forceinline__ unsigned packbf(float lo, float hi) {
  return ((unsigned)f2bf(hi) << 16) | (unsigned)f2bf(lo);
}
__device__ __forceinline__ float bflo(unsigned p) { return __uint_as_float(p << 16); }
__device__ __forceinline__ float bfhi(unsigned p) { return __uint_as_float(p & 0xffff0000u); }

// ---------------- combined: hist_rank (blocks 0..HIST_NB) + W repack --------
__global__ __launch_bounds__(256) void build_pre(const int* __restrict__ dst,
                                                 int* __restrict__ counts,
                                                 int* __restrict__ rank,
                                                 const float* __restrict__ W0,
                                                 const float* __restrict__ W1,
                                                 const float* __restrict__ W2,
                                                 const float* __restrict__ as0,
                                                 const float* __restrict__ as1,
                                                 const float* __restrict__ as2,
                                                 const float* __restrict__ ad0,
                                                 const float* __restrict__ ad1,
                                                 const float* __restrict__ ad2,
                                                 unsigned short* __restrict__ Wr) {
  int bid = blockIdx.x;
  if (bid < HIST_NB) {
    int i = bid * 256 + threadIdx.x;
    if (i >= ET) return;
    int d = (i < N_EDGES) ? dst[i] : i - N_EDGES;
    rank[i] = atomicAdd(&counts[d], 1);
    return;
  }
  int i = (bid - HIST_NB) * 256 + threadIdx.x;
  if (i >= 3 * WSTRIDE) return;
  int L = i / WSTRIDE, rem = i % WSTRIDE;
  int t  = rem >> 11;
  int ks = (rem >> 9) & 3;
  int ln = (rem >> 3) & 63;
  int j  = rem & 7;
  int k  = ks * 32 + (ln >> 4) * 8 + j;
  const float* W = (L == 0) ? W0 : ((L == 1) ? W1 : W2);
  float val;
  if (t < 8) {
    int col = t * 16 + (ln & 15);
    val = W[k * 128 + col];
  } else {
    int cl = ln & 15;
    if (cl < 4) {
      int head = cl & 1;
      const float* a = (cl < 2) ? ((L == 0) ? as0 : (L == 1) ? as1 : as2)
                                : ((L == 0) ? ad0 : (L == 1) ? ad1 : ad2);
      float s = 0.f;
      const float* wrow = W + k * 128 + head * 64;
      const float* ah = a + head * 64;
#pragma unroll 8
      for (int c = 0; c < 64; ++c) s = fmaf(wrow[c], ah[c], s);
      val = s * LOG2E;
    } else {
      val = 0.f;
    }
  }
  Wr[i] = f2bf(val);
}

// ---------------- CSR scan ----------------

__global__ __launch_bounds__(256) void scan_blk(const int* __restrict__ counts,
                                                int* __restrict__ rowptr,
                                                int* __restrict__ partials) {
  int i = blockIdx.x * 256 + threadIdx.x;
  int lane = threadIdx.x & 63, wv = threadIdx.x >> 6;
  int c = (i < N_NODES) ? counts[i] : 0;
  int v = c;
#pragma unroll
  for (int off = 1; off < 64; off <<= 1) {
    int u = __shfl_up(v, off);
    if (lane >= off) v += u;
  }
  __shared__ int wsum[4];
  if (lane == 63) wsum[wv] = v;
  __syncthreads();
  int add = 0;
  for (int w = 0; w < wv; ++w) add += wsum[w];
  if (i < N_NODES) rowptr[i] = v - c + add;
  if (threadIdx.x == 255) partials[blockIdx.x] = add + v;
}

__global__ __launch_bounds__(256) void scan_fin(int* __restrict__ rowptr,
                                                const int* __restrict__ partials) {
  __shared__ int sh[256];
  int t = threadIdx.x;
  sh[t] = (t < (int)blockIdx.x && t < SCAN_NB) ? partials[t] : 0;
  __syncthreads();
#pragma unroll
  for (int off = 128; off > 0; off >>= 1) {
    if (t < off) sh[t] += sh[t + off];
    __syncthreads();
  }
  int base = sh[0];
  int i = blockIdx.x * 256 + t;
  if (i < N_NODES) rowptr[i] += base;
  if (i == 0) rowptr[N_NODES] = ET;
}

__global__ __launch_bounds__(256) void scatter_pos(const int* __restrict__ src,
                                                   const int* __restrict__ dst,
                                                   const int* __restrict__ rowptr,
                                                   const int* __restrict__ rank,
                                                   int* __restrict__ csr_src) {
  int i = blockIdx.x * 256 + threadIdx.x;
  if (i >= ET) return;
  int d, s;
  if (i < N_EDGES) { d = dst[i]; s = src[i]; } else { d = s = i - N_EDGES; }
  csr_src[rowptr[d] + rank[i]] = s;
}

// ---------------- BN finalize: part[32][256] -> lsbuf[256]; zero part ------
__global__ __launch_bounds__(128) void bn_fin(float* __restrict__ part,
                                              const float* __restrict__ g,
                                              const float* __restrict__ be,
                                              float* __restrict__ lsbuf) {
  int t = threadIdx.x;   // 0..127
  float s = 0.f, q = 0.f;
#pragma unroll
  for (int k = 0; k < 32; ++k) {
    s += part[k * 256 + t];
    q += part[k * 256 + 128 + t];
    part[k * 256 + t] = 0.f;
    part[k * 256 + 128 + t] = 0.f;
  }
  float mu  = s * (1.f / N_NODES);
  float var = q * (1.f / N_NODES) - mu * mu;
  float sc  = rsqrtf(var + BN_EPS) * g[t];
  lsbuf[t]       = sc;
  lsbuf[128 + t] = be[t] - mu * sc;
}

// ---------------- MFMA gemm (9 tiles: 8 H cols + logit cols) — unchanged ---
__global__ __launch_bounds__(256) void gemm_mfma(const void* __restrict__ Xin,
                                                 const unsigned short* __restrict__ WrL,
                                                 const float* __restrict__ lsbuf,
                                                 unsigned short* __restrict__ Hbf,
                                                 float* __restrict__ als,
                                                 float* __restrict__ ald,
                                                 int inBF) {
  __shared__ unsigned short lds[4][16][128];
  __shared__ float ls_scale[128], ls_shift[128];
  int lane = threadIdx.x & 63;
  int wv   = threadIdx.x >> 6;

  if (inBF) {
    int t = threadIdx.x;
    if (t < 128) {
      ls_scale[t] = lsbuf[t];
      ls_shift[t] = lsbuf[128 + t];
    }
    __syncthreads();
  }

  int row0 = blockIdx.x * 64 + wv * 16;
  int gidx = lane & 15;
  int quad = lane >> 4;
  int rA   = row0 + gidx;
  int rAc  = rA < N_NODES ? rA : N_NODES - 1;
  int koff = quad * 8;

  f32x4 acc[9] = {};
#pragma unroll
  for (int ks = 0; ks < 4; ++ks) {
    int cb = ks * 32 + koff;
    float xv[8];
    if (inBF) {
      const uint4* xr = (const uint4*)((const unsigned*)Xin + (size_t)rAc * 64 + (cb >> 1));
      uint4 xa = *xr;
      xv[0] = bflo(xa.x); xv[1] = bfhi(xa.x);
      xv[2] = bflo(xa.y); xv[3] = bfhi(xa.y);
      xv[4] = bflo(xa.z); xv[5] = bfhi(xa.z);
      xv[6] = bflo(xa.w); xv[7] = bfhi(xa.w);
    } else {
      const float4* xr = (const float4*)((const float*)Xin + (size_t)rAc * FDIM + cb);
      float4 xa = xr[0], xb = xr[1];
      xv[0] = xa.x; xv[1] = xa.y; xv[2] = xa.z; xv[3] = xa.w;
      xv[4] = xb.x; xv[5] = xb.y; xv[6] = xb.z; xv[7] = xb.w;
    }
    bf16x8 afrag;
    if (inBF) {
#pragma unroll
      for (int j = 0; j < 8; ++j) {
        int c = cb + j;
        float v = fmaf(xv[j], ls_scale[c], ls_shift[c]);
        v = v > 0.f ? v : 0.f;
        afrag[j] = (short)f2bf(v);
      }
    } else {
#pragma unroll
      for (int j = 0; j < 8; ++j) afrag[j] = (short)f2bf(xv[j]);
    }
#pragma unroll
    for (int t = 0; t < 9; ++t) {
      bf16x8 bfrag = *(const bf16x8*)(WrL + ((size_t)((t * 4 + ks) * 64 + lane)) * 8);
      acc[t] = __builtin_amdgcn_mfma_f32_16x16x32_bf16(afrag, bfrag, acc[t], 0, 0, 0);
    }
  }

  if (gidx < 4) {
    float* dp = (gidx < 2) ? als : ald;
    int hd = gidx & 1;
#pragma unroll
    for (int r = 0; r < 4; ++r) {
      int row = row0 + quad * 4 + r;
      if (row < N_NODES) dp[row * 2 + hd] = acc[8][r];
    }
  }

#pragma unroll
  for (int t = 0; t < 8; ++t)
#pragma unroll
    for (int r = 0; r < 4; ++r)
      lds[wv][quad * 4 + r][t * 16 + gidx] = f2bf(acc[t][r]);
  __syncthreads();
#pragma unroll
  for (int it = 0; it < 4; ++it) {
    int rloc = it * 4 + quad;
    int row = row0 + rloc;
    if (row < N_NODES)
      *(u16x8*)(Hbf + (size_t)row * FDIM + gidx * 8) = *(u16x8*)&lds[wv][rloc][gidx * 8];
  }
}

// ---------------- fused softmax-aggregate (adaptive tail + BN epilogue) ----
// One wave per node; lane owns channels 2l,2l+1; lanes 0-31 head 0,
// 32-63 head 1. exp2 logits (log2e baked into W*a), no max shift.
// 8-deep register prefetch; main loop unclamped; peeled last iteration
// prefetches the tail at width 8 / 4 / 0; tail STEPs gated wave-uniformly.
// mode 0: write Abf bf16-pair + BN sums via LDS reduction + atomics into
// part[32][256] (R14 epilogue). mode 2: head-mean + b2 -> out fp32 [N,64].
__global__ __launch_bounds__(256) void fused_agg(const int* __restrict__ rowptr,
                                                 const int* __restrict__ csr_src,
                                                 const unsigned* __restrict__ H2,
                                                 const float* __restrict__ als,
                                                 const float* __restrict__ ald,
                                                 unsigned* __restrict__ Abf,
                                                 float* __restrict__ out,
                                                 const float* __restrict__ b2,
                                                 float* __restrict__ part,
                                                 int mode) {
  int lane = threadIdx.x & 63;
  bool hi = lane >= 32;
  int n = __builtin_amdgcn_readfirstlane((blockIdx.x * 256 + threadIdx.x) >> 6);
  int beg = rowptr[n], end = rowptr[n + 1];
  int deg = end - beg;                   // >= 1 (self loop)
  int last = end - 1;
  float2 adv = ((const float2*)ald)[n];
  float advh = hi ? adv.y : adv.x;

  int nfull = deg >> 3;
  int rem = deg & 7;

  // prologue: block 0 (clamped; exact when deg>=8)
  int sa[8]; float2 aa[8]; unsigned ha[8];
#pragma unroll
  for (int i = 0; i < 8; ++i) {
    int idx = beg + i; idx = idx > last ? last : idx;
    sa[i] = csr_src[idx];
  }
#pragma unroll
  for (int i = 0; i < 8; ++i) {
    aa[i] = ((const float2*)als)[sa[i]];
    ha[i] = H2[(size_t)sa[i] * 64 + lane];
  }

  float l = 0.f, ox = 0.f, oy = 0.f;

#define STEPU(i) { \
    float v_ = (hi ? aa[i].y : aa[i].x) + advh; \
    v_ = fmaxf(v_, SLOPE * v_); \
    float e_ = exp2f(v_); \
    l += e_; \
    ox = fmaf(e_, bflo(ha[i]), ox); \
    oy = fmaf(e_, bfhi(ha[i]), oy); }
#define STEPM(i) { if (i < rem) STEPU(i) }

  // main loop: compute block b-1, prefetch full block b (exact, unclamped)
  for (int b = 1; b < nfull; ++b) {
    int base = beg + b * 8;
    int sn[8]; float2 an[8]; unsigned hn[8];
#pragma unroll
    for (int i = 0; i < 8; ++i) sn[i] = csr_src[base + i];
#pragma unroll
    for (int i = 0; i < 8; ++i) {
      an[i] = ((const float2*)als)[sn[i]];
      hn[i] = H2[(size_t)sn[i] * 64 + lane];
    }
    STEPU(0); STEPU(1); STEPU(2); STEPU(3);
    STEPU(4); STEPU(5); STEPU(6); STEPU(7);
#pragma unroll
    for (int i = 0; i < 8; ++i) { aa[i] = an[i]; ha[i] = hn[i]; }
  }

  // peeled last full-block iteration: prefetch tail at adaptive width
  if (nfull) {
    int base = beg + nfull * 8;
    int sn[8]; float2 an[8]; unsigned hn[8];
    if (rem > 4) {
#pragma unroll
      for (int i = 0; i < 8; ++i) {
        int idx = base + i; idx = idx > last ? last : idx;
        sn[i] = csr_src[idx];
      }
#pragma unroll
      for (int i = 0; i < 8; ++i) {
        an[i] = ((const float2*)als)[sn[i]];
        hn[i] = H2[(size_t)sn[i] * 64 + lane];
      }
    } else if (rem) {
#pragma unroll
      for (int i = 0; i < 4; ++i) {
        int idx = base + i; idx = idx > last ? last : idx;
        sn[i] = csr_src[idx];
      }
#pragma unroll
      for (int i = 0; i < 4; ++i) {
        an[i] = ((const float2*)als)[sn[i]];
        hn[i] = H2[(size_t)sn[i] * 64 + lane];
      }
    }
    STEPU(0); STEPU(1); STEPU(2); STEPU(3);
    STEPU(4); STEPU(5); STEPU(6); STEPU(7);
    if (rem > 4) {
#pragma unroll
      for (int i = 0; i < 8; ++i) { aa[i] = an[i]; ha[i] = hn[i]; }
    } else if (rem) {
#pragma unroll
      for (int i = 0; i < 4; ++i) { aa[i] = an[i]; ha[i] = hn[i]; }
    }
  }

  // tail: wave-uniform gated STEPs
  if (rem > 4) {
    STEPM(0); STEPM(1); STEPM(2); STEPM(3);
    STEPM(4); STEPM(5); STEPM(6); STEPM(7);
  } else if (rem) {
    STEPM(0); STEPM(1); STEPM(2); STEPM(3);
  }
#undef STEPU
#undef STEPM

  float inv = 1.f / (l + 1e-16f);
  ox *= inv; oy *= inv;

  if (mode == 0) {
    Abf[(size_t)n * 64 + lane] = packbf(ox, oy);
    __shared__ float sh[4][4][64];
    int wv = threadIdx.x >> 6;
    sh[wv][0][lane] = ox;
    sh[wv][1][lane] = oy;
    sh[wv][2][lane] = ox * ox;
    sh[wv][3][lane] = oy * oy;
    __syncthreads();
    if (threadIdx.x < 64) {
      int t = threadIdx.x;
      float a0 = 0.f, a1 = 0.f, a2 = 0.f, a3 = 0.f;
#pragma unroll
      for (int w = 0; w < 4; ++w) {
        a0 += sh[w][0][t]; a1 += sh[w][1][t];
        a2 += sh[w][2][t]; a3 += sh[w][3][t];
      }
      float* slot = part + (blockIdx.x & 31) * 256;
      atomicAdd(&slot[2 * t],           a0);
      atomicAdd(&slot[2 * t + 1],       a1);
      atomicAdd(&slot[128 + 2 * t],     a2);
      atomicAdd(&slot[128 + 2 * t + 1], a3);
    }
  } else {
    float px = __shfl_xor(ox, 32);
    float py = __shfl_xor(oy, 32);
    if (lane < 32) {
      int c = lane * 2;
      float2 outv = {0.5f * (ox + px) + b2[c], 0.5f * (oy + py) + b2[c + 1]};
      *(float2*)(out + (size_t)n * 64 + c) = outv;
    }
  }
}

extern "C" void kernel_launch(void* const* d_in, const int* in_sizes, int n_in,
                              void* d_out, int out_size, void* d_ws, size_t ws_size,
                              hipStream_t stream) {
  const float* x  = (const float*)d_in[0];
  const int*   ei = (const int*)d_in[1];
  const int* src = ei;
  const int* dst = ei + N_EDGES;

  const float* W[3]    = {(const float*)d_in[2],  (const float*)d_in[8],  (const float*)d_in[14]};
  const float* asrc[3] = {(const float*)d_in[3],  (const float*)d_in[9],  (const float*)d_in[15]};
  const float* adst[3] = {(const float*)d_in[4],  (const float*)d_in[10], (const float*)d_in[16]};
  const float* g[2]    = {(const float*)d_in[6],  (const float*)d_in[12]};
  const float* be[2]   = {(const float*)d_in[7],  (const float*)d_in[13]};
  const float* b2      = (const float*)d_in[17];

  // workspace (4-byte units, regions 16B-aligned) — byte-identical to R14.
  // counts and part adjacent -> ONE memset zeroes both; bn_fin re-zeroes part.
  int*   counts   = (int*)d_ws;                  // 50048
  float* part     = (float*)(counts + 50048);    // 8192 (32x256 BN slots)
  int*   rowptr   = (int*)(part + 8192);         // 50048
  int*   partials = rowptr + 50048;              // 256
  int*   rank     = partials + 256;              // 850048
  int*   csr_src  = rank + 850048;               // 850048
  float* lsbuf    = (float*)(csr_src + 850048);  // 256 scale|shift
  float* als      = lsbuf + 256;                 // 100096
  float* ald      = als + 100096;                // 100096
  unsigned short* Wr  = (unsigned short*)(ald + 100096);   // 3*WSTRIDE u16
  unsigned short* Hbf = Wr + 3 * WSTRIDE + 128;            // pad to 16B align
  unsigned* Abf   = (unsigned*)(Hbf + (size_t)N_NODES * FDIM);

  // ---- setup: zero counts+part, hist+repack, scan, scatter ----
  hipMemsetAsync(counts, 0, (50048 + 8192) * sizeof(int), stream);
  build_pre<<<HIST_NB + RPK_NB, 256, 0, stream>>>(
      dst, counts, rank, W[0], W[1], W[2],
      asrc[0], asrc[1], asrc[2], adst[0], adst[1], adst[2], Wr);
  scan_blk<<<SCAN_NB, 256, 0, stream>>>(counts, rowptr, partials);
  scan_fin<<<SCAN_NB, 256, 0, stream>>>(rowptr, partials);
  scatter_pos<<<(ET + 255) / 256, 256, 0, stream>>>(src, dst, rowptr, rank, csr_src);

  const int gemm_grid = (N_NODES + 63) / 64;
  const int agg_grid  = N_NODES * 64 / 256;   // 12500, one wave per node

  for (int L = 0; L < 3; ++L) {
    const void* fin = (L == 0) ? (const void*)x : (const void*)Abf;
    int inBF = (L > 0);
    gemm_mfma<<<gemm_grid, 256, 0, stream>>>(fin, Wr + (size_t)L * WSTRIDE, lsbuf,
                                             Hbf, als, ald, inBF);
    fused_agg<<<agg_grid, 256, 0, stream>>>(rowptr, csr_src, (const unsigned*)Hbf,
                                            als, ald, Abf, (float*)d_out, b2, part,
                                            (L == 2) ? 2 : 0);
    if (L < 2)
      bn_fin<<<1, 128, 0, stream>>>(part, g[L], be[L], lsbuf);
  }
}

// Round 8
// 323.300 us; speedup vs baseline: 1.6153x; 1.0057x over previous
//
#include <hip/hip_runtime.h>

// GAT 3-layer (N=50000, E=800000 (+N self loops), H=2, C=64, widths 128)
// Round 22: remove bn_fin from the critical path. R21 post-mortem: all owned
// kernels < 44us; remaining ~195us is invisible dispatches + launch gaps.
// bn_fin (2x single-block latency-bound dispatches, est 15-25us combined
// incl. gaps) is folded into gemm_mfma: every block redundantly reduces
// part[32][256] -> 128 scale/shift pairs at inBF start (32 adds/thread from
// L2-hot 32KB; ~1us aggregate). Re-zero hazard solved by double-buffered
// partials: L0 -> part0 (memset slot), L1 -> part1 (aliases dead rank[],
// zeroed by blocks 0..31 of gemm L1). 11 -> 9 dispatches. Workspace layout
// byte-identical to R14/R21. fused_agg unchanged from R21.

#define N_NODES 50000
#define N_EDGES 800000
#define ET (N_EDGES + N_NODES)   // 850000 incl self loops
#define FDIM 128
#define SLOPE 0.2f
#define BN_EPS 1e-5f
#define SCAN_NB 196              // ceil(50000/256)
#define HIST_NB 3321             // ceil(ET/256)
#define RPK_NB 216               // ceil(3*WSTRIDE/256)
#define LOG2E 1.44269504088896340736f
#define WSTRIDE 18432            // 9 tiles * 4 ks * 64 lanes * 8

typedef __attribute__((ext_vector_type(8))) short bf16x8;
typedef __attribute__((ext_vector_type(4))) float f32x4;
typedef __attribute__((ext_vector_type(8))) unsigned short u16x8;

__device__ __forceinline__ unsigned short f2bf(float f) {
  unsigned u = __float_as_uint(f);
  u = u + 0x7fffu + ((u >> 16) & 1u);   // RNE
  return (unsigned short)(u >> 16);
}
__device__ __forceinline__ unsigned packbf(float lo, float hi) {
  return ((unsigned)f2bf(hi) << 16) | (unsigned)f2bf(lo);
}
__device__ __forceinline__ float bflo(unsigned p) { return __uint_as_float(p << 16); }
__device__ __forceinline__ float bfhi(unsigned p) { return __uint_as_float(p & 0xffff0000u); }

// ---------------- combined: hist_rank (blocks 0..HIST_NB) + W repack --------
__global__ __launch_bounds__(256) void build_pre(const int* __restrict__ dst,
                                                 int* __restrict__ counts,
                                                 int* __restrict__ rank,
                                                 const float* __restrict__ W0,
                                                 const float* __restrict__ W1,
                                                 const float* __restrict__ W2,
                                                 const float* __restrict__ as0,
                                                 const float* __restrict__ as1,
                                                 const float* __restrict__ as2,
                                                 const float* __restrict__ ad0,
                                                 const float* __restrict__ ad1,
                                                 const float* __restrict__ ad2,
                                                 unsigned short* __restrict__ Wr) {
  int bid = blockIdx.x;
  if (bid < HIST_NB) {
    int i = bid * 256 + threadIdx.x;
    if (i >= ET) return;
    int d = (i < N_EDGES) ? dst[i] : i - N_EDGES;
    rank[i] = atomicAdd(&counts[d], 1);
    return;
  }
  int i = (bid - HIST_NB) * 256 + threadIdx.x;
  if (i >= 3 * WSTRIDE) return;
  int L = i / WSTRIDE, rem = i % WSTRIDE;
  int t  = rem >> 11;
  int ks = (rem >> 9) & 3;
  int ln = (rem >> 3) & 63;
  int j  = rem & 7;
  int k  = ks * 32 + (ln >> 4) * 8 + j;
  const float* W = (L == 0) ? W0 : ((L == 1) ? W1 : W2);
  float val;
  if (t < 8) {
    int col = t * 16 + (ln & 15);
    val = W[k * 128 + col];
  } else {
    int cl = ln & 15;
    if (cl < 4) {
      int head = cl & 1;
      const float* a = (cl < 2) ? ((L == 0) ? as0 : (L == 1) ? as1 : as2)
                                : ((L == 0) ? ad0 : (L == 1) ? ad1 : ad2);
      float s = 0.f;
      const float* wrow = W + k * 128 + head * 64;
      const float* ah = a + head * 64;
#pragma unroll 8
      for (int c = 0; c < 64; ++c) s = fmaf(wrow[c], ah[c], s);
      val = s * LOG2E;
    } else {
      val = 0.f;
    }
  }
  Wr[i] = f2bf(val);
}

// ---------------- CSR scan ----------------

__global__ __launch_bounds__(256) void scan_blk(const int* __restrict__ counts,
                                                int* __restrict__ rowptr,
                                                int* __restrict__ partials) {
  int i = blockIdx.x * 256 + threadIdx.x;
  int lane = threadIdx.x & 63, wv = threadIdx.x >> 6;
  int c = (i < N_NODES) ? counts[i] : 0;
  int v = c;
#pragma unroll
  for (int off = 1; off < 64; off <<= 1) {
    int u = __shfl_up(v, off);
    if (lane >= off) v += u;
  }
  __shared__ int wsum[4];
  if (lane == 63) wsum[wv] = v;
  __syncthreads();
  int add = 0;
  for (int w = 0; w < wv; ++w) add += wsum[w];
  if (i < N_NODES) rowptr[i] = v - c + add;
  if (threadIdx.x == 255) partials[blockIdx.x] = add + v;
}

__global__ __launch_bounds__(256) void scan_fin(int* __restrict__ rowptr,
                                                const int* __restrict__ partials) {
  __shared__ int sh[256];
  int t = threadIdx.x;
  sh[t] = (t < (int)blockIdx.x && t < SCAN_NB) ? partials[t] : 0;
  __syncthreads();
#pragma unroll
  for (int off = 128; off > 0; off >>= 1) {
    if (t < off) sh[t] += sh[t + off];
    __syncthreads();
  }
  int base = sh[0];
  int i = blockIdx.x * 256 + t;
  if (i < N_NODES) rowptr[i] += base;
  if (i == 0) rowptr[N_NODES] = ET;
}

__global__ __launch_bounds__(256) void scatter_pos(const int* __restrict__ src,
                                                   const int* __restrict__ dst,
                                                   const int* __restrict__ rowptr,
                                                   const int* __restrict__ rank,
                                                   int* __restrict__ csr_src) {
  int i = blockIdx.x * 256 + threadIdx.x;
  if (i >= ET) return;
  int d, s;
  if (i < N_EDGES) { d = dst[i]; s = src[i]; } else { d = s = i - N_EDGES; }
  csr_src[rowptr[d] + rank[i]] = s;
}

// ---------------- MFMA gemm (9 tiles: 8 H cols + logit cols) ---------------
// inBF==1: BN scale/shift computed IN-BLOCK from partRead[32][256] (sum |
// sumsq per channel), replacing the old bn_fin kernel; blocks 0..31 also
// zero partZero (the next layer's accumulation buffer).
__global__ __launch_bounds__(256) void gemm_mfma(const void* __restrict__ Xin,
                                                 const unsigned short* __restrict__ WrL,
                                                 const float* __restrict__ g,
                                                 const float* __restrict__ be,
                                                 const float* __restrict__ partRead,
                                                 float* __restrict__ partZero,
                                                 unsigned short* __restrict__ Hbf,
                                                 float* __restrict__ als,
                                                 float* __restrict__ ald,
                                                 int inBF) {
  __shared__ unsigned short lds[4][16][128];
  __shared__ float ls_scale[128], ls_shift[128];
  int lane = threadIdx.x & 63;
  int wv   = threadIdx.x >> 6;

  if (inBF) {
    int t = threadIdx.x;
    int c = t & 127, st = t >> 7;      // st 0: sum, 1: sumsq
    float a = 0.f;
#pragma unroll
    for (int k = 0; k < 32; ++k) a += partRead[k * 256 + st * 128 + c];
    __shared__ float sstat[2][128];
    sstat[st][c] = a;
    if (blockIdx.x < 32) partZero[blockIdx.x * 256 + t] = 0.f;
    __syncthreads();
    if (t < 128) {
      float mu  = sstat[0][t] * (1.f / N_NODES);
      float var = sstat[1][t] * (1.f / N_NODES) - mu * mu;
      float sc  = rsqrtf(var + BN_EPS) * g[t];
      ls_scale[t] = sc;
      ls_shift[t] = be[t] - mu * sc;
    }
    __syncthreads();
  }

  int row0 = blockIdx.x * 64 + wv * 16;
  int gidx = lane & 15;
  int quad = lane >> 4;
  int rA   = row0 + gidx;
  int rAc  = rA < N_NODES ? rA : N_NODES - 1;
  int koff = quad * 8;

  f32x4 acc[9] = {};
#pragma unroll
  for (int ks = 0; ks < 4; ++ks) {
    int cb = ks * 32 + koff;
    float xv[8];
    if (inBF) {
      const uint4* xr = (const uint4*)((const unsigned*)Xin + (size_t)rAc * 64 + (cb >> 1));
      uint4 xa = *xr;
      xv[0] = bflo(xa.x); xv[1] = bfhi(xa.x);
      xv[2] = bflo(xa.y); xv[3] = bfhi(xa.y);
      xv[4] = bflo(xa.z); xv[5] = bfhi(xa.z);
      xv[6] = bflo(xa.w); xv[7] = bfhi(xa.w);
    } else {
      const float4* xr = (const float4*)((const float*)Xin + (size_t)rAc * FDIM + cb);
      float4 xa = xr[0], xb = xr[1];
      xv[0] = xa.x; xv[1] = xa.y; xv[2] = xa.z; xv[3] = xa.w;
      xv[4] = xb.x; xv[5] = xb.y; xv[6] = xb.z; xv[7] = xb.w;
    }
    bf16x8 afrag;
    if (inBF) {
#pragma unroll
      for (int j = 0; j < 8; ++j) {
        int c = cb + j;
        float v = fmaf(xv[j], ls_scale[c], ls_shift[c]);
        v = v > 0.f ? v : 0.f;
        afrag[j] = (short)f2bf(v);
      }
    } else {
#pragma unroll
      for (int j = 0; j < 8; ++j) afrag[j] = (short)f2bf(xv[j]);
    }
#pragma unroll
    for (int t = 0; t < 9; ++t) {
      bf16x8 bfrag = *(const bf16x8*)(WrL + ((size_t)((t * 4 + ks) * 64 + lane)) * 8);
      acc[t] = __builtin_amdgcn_mfma_f32_16x16x32_bf16(afrag, bfrag, acc[t], 0, 0, 0);
    }
  }

  if (gidx < 4) {
    float* dp = (gidx < 2) ? als : ald;
    int hd = gidx & 1;
#pragma unroll
    for (int r = 0; r < 4; ++r) {
      int row = row0 + quad * 4 + r;
      if (row < N_NODES) dp[row * 2 + hd] = acc[8][r];
    }
  }

#pragma unroll
  for (int t = 0; t < 8; ++t)
#pragma unroll
    for (int r = 0; r < 4; ++r)
      lds[wv][quad * 4 + r][t * 16 + gidx] = f2bf(acc[t][r]);
  __syncthreads();
#pragma unroll
  for (int it = 0; it < 4; ++it) {
    int rloc = it * 4 + quad;
    int row = row0 + rloc;
    if (row < N_NODES)
      *(u16x8*)(Hbf + (size_t)row * FDIM + gidx * 8) = *(u16x8*)&lds[wv][rloc][gidx * 8];
  }
}

// ---------------- fused softmax-aggregate (adaptive tail + BN epilogue) ----
// One wave per node; lane owns channels 2l,2l+1; lanes 0-31 head 0,
// 32-63 head 1. exp2 logits (log2e baked into W*a), no max shift.
// 8-deep register prefetch; main loop unclamped; peeled last iteration
// prefetches the tail at width 8 / 4 / 0; tail STEPs gated wave-uniformly.
// mode 0: write Abf bf16-pair + BN sums via LDS reduction + atomics into
// part[32][256]. mode 2: head-mean + b2 -> out fp32 [N,64].
__global__ __launch_bounds__(256) void fused_agg(const int* __restrict__ rowptr,
                                                 const int* __restrict__ csr_src,
                                                 const unsigned* __restrict__ H2,
                                                 const float* __restrict__ als,
                                                 const float* __restrict__ ald,
                                                 unsigned* __restrict__ Abf,
                                                 float* __restrict__ out,
                                                 const float* __restrict__ b2,
                                                 float* __restrict__ part,
                                                 int mode) {
  int lane = threadIdx.x & 63;
  bool hi = lane >= 32;
  int n = __builtin_amdgcn_readfirstlane((blockIdx.x * 256 + threadIdx.x) >> 6);
  int beg = rowptr[n], end = rowptr[n + 1];
  int deg = end - beg;                   // >= 1 (self loop)
  int last = end - 1;
  float2 adv = ((const float2*)ald)[n];
  float advh = hi ? adv.y : adv.x;

  int nfull = deg >> 3;
  int rem = deg & 7;

  // prologue: block 0 (clamped; exact when deg>=8)
  int sa[8]; float2 aa[8]; unsigned ha[8];
#pragma unroll
  for (int i = 0; i < 8; ++i) {
    int idx = beg + i; idx = idx > last ? last : idx;
    sa[i] = csr_src[idx];
  }
#pragma unroll
  for (int i = 0; i < 8; ++i) {
    aa[i] = ((const float2*)als)[sa[i]];
    ha[i] = H2[(size_t)sa[i] * 64 + lane];
  }

  float l = 0.f, ox = 0.f, oy = 0.f;

#define STEPU(i) { \
    float v_ = (hi ? aa[i].y : aa[i].x) + advh; \
    v_ = fmaxf(v_, SLOPE * v_); \
    float e_ = exp2f(v_); \
    l += e_; \
    ox = fmaf(e_, bflo(ha[i]), ox); \
    oy = fmaf(e_, bfhi(ha[i]), oy); }
#define STEPM(i) { if (i < rem) STEPU(i) }

  // main loop: compute block b-1, prefetch full block b (exact, unclamped)
  for (int b = 1; b < nfull; ++b) {
    int base = beg + b * 8;
    int sn[8]; float2 an[8]; unsigned hn[8];
#pragma unroll
    for (int i = 0; i < 8; ++i) sn[i] = csr_src[base + i];
#pragma unroll
    for (int i = 0; i < 8; ++i) {
      an[i] = ((const float2*)als)[sn[i]];
      hn[i] = H2[(size_t)sn[i] * 64 + lane];
    }
    STEPU(0); STEPU(1); STEPU(2); STEPU(3);
    STEPU(4); STEPU(5); STEPU(6); STEPU(7);
#pragma unroll
    for (int i = 0; i < 8; ++i) { aa[i] = an[i]; ha[i] = hn[i]; }
  }

  // peeled last full-block iteration: prefetch tail at adaptive width
  if (nfull) {
    int base = beg + nfull * 8;
    int sn[8]; float2 an[8]; unsigned hn[8];
    if (rem > 4) {
#pragma unroll
      for (int i = 0; i < 8; ++i) {
        int idx = base + i; idx = idx > last ? last : idx;
        sn[i] = csr_src[idx];
      }
#pragma unroll
      for (int i = 0; i < 8; ++i) {
        an[i] = ((const float2*)als)[sn[i]];
        hn[i] = H2[(size_t)sn[i] * 64 + lane];
      }
    } else if (rem) {
#pragma unroll
      for (int i = 0; i < 4; ++i) {
        int idx = base + i; idx = idx > last ? last : idx;
        sn[i] = csr_src[idx];
      }
#pragma unroll
      for (int i = 0; i < 4; ++i) {
        an[i] = ((const float2*)als)[sn[i]];
        hn[i] = H2[(size_t)sn[i] * 64 + lane];
      }
    }
    STEPU(0); STEPU(1); STEPU(2); STEPU(3);
    STEPU(4); STEPU(5); STEPU(6); STEPU(7);
    if (rem > 4) {
#pragma unroll
      for (int i = 0; i < 8; ++i) { aa[i] = an[i]; ha[i] = hn[i]; }
    } else if (rem) {
#pragma unroll
      for (int i = 0; i < 4; ++i) { aa[i] = an[i]; ha[i] = hn[i]; }
    }
  }

  // tail: wave-uniform gated STEPs
  if (rem > 4) {
    STEPM(0); STEPM(1); STEPM(2); STEPM(3);
    STEPM(4); STEPM(5); STEPM(6); STEPM(7);
  } else if (rem) {
    STEPM(0); STEPM(1); STEPM(2); STEPM(3);
  }
#undef STEPU
#undef STEPM

  float inv = 1.f / (l + 1e-16f);
  ox *= inv; oy *= inv;

  if (mode == 0) {
    Abf[(size_t)n * 64 + lane] = packbf(ox, oy);
    __shared__ float sh[4][4][64];
    int wv = threadIdx.x >> 6;
    sh[wv][0][lane] = ox;
    sh[wv][1][lane] = oy;
    sh[wv][2][lane] = ox * ox;
    sh[wv][3][lane] = oy * oy;
    __syncthreads();
    if (threadIdx.x < 64) {
      int t = threadIdx.x;
      float a0 = 0.f, a1 = 0.f, a2 = 0.f, a3 = 0.f;
#pragma unroll
      for (int w = 0; w < 4; ++w) {
        a0 += sh[w][0][t]; a1 += sh[w][1][t];
        a2 += sh[w][2][t]; a3 += sh[w][3][t];
      }
      float* slot = part + (blockIdx.x & 31) * 256;
      atomicAdd(&slot[2 * t],           a0);
      atomicAdd(&slot[2 * t + 1],       a1);
      atomicAdd(&slot[128 + 2 * t],     a2);
      atomicAdd(&slot[128 + 2 * t + 1], a3);
    }
  } else {
    float px = __shfl_xor(ox, 32);
    float py = __shfl_xor(oy, 32);
    if (lane < 32) {
      int c = lane * 2;
      float2 outv = {0.5f * (ox + px) + b2[c], 0.5f * (oy + py) + b2[c + 1]};
      *(float2*)(out + (size_t)n * 64 + c) = outv;
    }
  }
}

extern "C" void kernel_launch(void* const* d_in, const int* in_sizes, int n_in,
                              void* d_out, int out_size, void* d_ws, size_t ws_size,
                              hipStream_t stream) {
  const float* x  = (const float*)d_in[0];
  const int*   ei = (const int*)d_in[1];
  const int* src = ei;
  const int* dst = ei + N_EDGES;

  const float* W[3]    = {(const float*)d_in[2],  (const float*)d_in[8],  (const float*)d_in[14]};
  const float* asrc[3] = {(const float*)d_in[3],  (const float*)d_in[9],  (const float*)d_in[15]};
  const float* adst[3] = {(const float*)d_in[4],  (const float*)d_in[10], (const float*)d_in[16]};
  const float* g[2]    = {(const float*)d_in[6],  (const float*)d_in[12]};
  const float* be[2]   = {(const float*)d_in[7],  (const float*)d_in[13]};
  const float* b2      = (const float*)d_in[17];

  // workspace (4-byte units, regions 16B-aligned) — byte-identical to R14.
  int*   counts   = (int*)d_ws;                  // 50048
  float* part0    = (float*)(counts + 50048);    // 8192 (layer-0 BN slots)
  int*   rowptr   = (int*)(part0 + 8192);        // 50048
  int*   partials = rowptr + 50048;              // 256
  int*   rank     = partials + 256;              // 850048
  int*   csr_src  = rank + 850048;               // 850048
  float* lsbuf    = (float*)(csr_src + 850048);  // 256 (legacy, unused)
  float* als      = lsbuf + 256;                 // 100096
  float* ald      = als + 100096;                // 100096
  unsigned short* Wr  = (unsigned short*)(ald + 100096);   // 3*WSTRIDE u16
  unsigned short* Hbf = Wr + 3 * WSTRIDE + 128;            // pad to 16B align
  unsigned* Abf   = (unsigned*)(Hbf + (size_t)N_NODES * FDIM);

  // layer-1 BN slots alias the dead rank[] buffer (rank dead after
  // scatter_pos; zeroed by blocks 0..31 of gemm L1 before fused_agg L1).
  float* part1 = (float*)rank;

  // ---- setup: zero counts+part0, hist+repack, scan, scatter ----
  hipMemsetAsync(counts, 0, (50048 + 8192) * sizeof(int), stream);
  build_pre<<<HIST_NB + RPK_NB, 256, 0, stream>>>(
      dst, counts, rank, W[0], W[1], W[2],
      asrc[0], asrc[1], asrc[2], adst[0], adst[1], adst[2], Wr);
  scan_blk<<<SCAN_NB, 256, 0, stream>>>(counts, rowptr, partials);
  scan_fin<<<SCAN_NB, 256, 0, stream>>>(rowptr, partials);
  scatter_pos<<<(ET + 255) / 256, 256, 0, stream>>>(src, dst, rowptr, rank, csr_src);

  const int gemm_grid = (N_NODES + 63) / 64;
  const int agg_grid  = N_NODES * 64 / 256;   // 12500, one wave per node

  // per-layer BN plumbing: gemm reads prior layer's partials, zeroes the
  // buffer the NEXT fused_agg will accumulate into.
  const float* partRd[3] = { part0, part0, part1 };   // L0 unused
  float*       partZr[3] = { part1, part1, part0 };   // L0 unused; L2 harmless
  float*       partWr[3] = { part0, part1, part0 };   // L2 unused
  const float* gL[3]  = { g[0],  g[0],  g[1]  };      // L0 unused
  const float* beL[3] = { be[0], be[0], be[1] };      // L0 unused

  for (int L = 0; L < 3; ++L) {
    const void* fin = (L == 0) ? (const void*)x : (const void*)Abf;
    int inBF = (L > 0);
    gemm_mfma<<<gemm_grid, 256, 0, stream>>>(fin, Wr + (size_t)L * WSTRIDE,
                                             gL[L], beL[L], partRd[L], partZr[L],
                                             Hbf, als, ald, inBF);
    fused_agg<<<agg_grid, 256, 0, stream>>>(rowptr, csr_src, (const unsigned*)Hbf,
                                            als, ald, Abf, (float*)d_out, b2,
                                            partWr[L], (L == 2) ? 2 : 0);
  }
}